// Round 4
// baseline (93.370 us; speedup 1.0000x reference)
//
#include <hip/hip_runtime.h>

// Problem constants (reference shapes)
#define BQ 16
#define NP 4096
#define MP 4096

constexpr int TPB = 256;                         // 4 waves
constexpr int WAVES = 4;
constexpr int FR = 4;                            // B-fragments (source groups of 32) per wave
constexpr int SRC_PER_BLOCK = 32 * FR * WAVES;   // 512
constexpr int TGT_PER_BLOCK = 1024;              // M-split 4
constexpr int CHUNK = 256;                       // targets staged per LDS chunk (8 KB)

typedef __bf16 bf16x8 __attribute__((ext_vector_type(8)));
typedef float f32x16 __attribute__((ext_vector_type(16)));

union Frag {
    unsigned short u[8];
    bf16x8 v;
    int4 i4;
};

// RNE float -> bf16 bits (no NaN inputs here)
__device__ inline unsigned short f2bf(float f) {
    unsigned u = __float_as_uint(f);
    return (unsigned short)((u + 0x7FFFu + ((u >> 16) & 1u)) >> 16);
}
__device__ inline float bf2f(unsigned short h) {
    return __uint_as_float(((unsigned)h) << 16);
}

// ---------------------------------------------------------------------------
// Prep: expand every "row-side" point (dir0: targets, dir1: sources) into its
// two 16B bf16 K-planes, stored contiguously (32 B/point) in the table.
// Also init minbuf to +inf and zero the output scalar.
// idx = (dir*16 + b)*4096 + t, 131072 threads.
// ---------------------------------------------------------------------------
__global__ __launch_bounds__(TPB) void chamfer_prep_kernel(
    const float* __restrict__ srcp, const float* __restrict__ tgtp,
    unsigned short* __restrict__ table, unsigned int* __restrict__ minbuf,
    float* __restrict__ out) {
    const int idx = blockIdx.x * TPB + threadIdx.x;  // 0..131071
    const int dir = idx >> 16;
    const int rem = idx & 65535;
    const float* rows = dir ? srcp : tgtp;           // A-side points
    const float* p = rows + (size_t)rem * 3;
    float x = p[0], y = p[1], z = p[2];
    unsigned short xh = f2bf(x), yh = f2bf(y), zh = f2bf(z);
    unsigned short xl = f2bf(x - bf2f(xh));
    unsigned short yl = f2bf(y - bf2f(yh));
    unsigned short zl = f2bf(z - bf2f(zh));
    float t2 = fmaf(x, x, fmaf(y, y, z * z));
    unsigned short t2h = f2bf(t2), t2l = f2bf(t2 - bf2f(t2h));
    const unsigned short ONE = 0x3F80;
    Frag p0, p1;
    p0.u[0] = xh; p0.u[1] = yh; p0.u[2] = zh;   // k0..2: hi (pairs with -2s hi)
    p0.u[3] = xh; p0.u[4] = yh; p0.u[5] = zh;   // k3..5: hi (pairs with -2s lo)
    p0.u[6] = xl; p0.u[7] = yl;                 // k6..7: lo x,y (pairs with -2s hi)
    p1.u[0] = zl;                               // k8: lo z
    p1.u[1] = t2h; p1.u[2] = t2l;               // k9..10: t2 (x 1)
    p1.u[3] = ONE; p1.u[4] = ONE;               // k11..12: 1 (x s2 hi/lo)
    p1.u[5] = 0; p1.u[6] = 0; p1.u[7] = 0;
    int4* dst = (int4*)(table + (size_t)idx * 16);
    dst[0] = p0.i4;
    dst[1] = p1.i4;
    minbuf[idx] = 0x7F800000u;  // +inf
    if (idx == 0) out[0] = 0.0f;
}

// ---------------------------------------------------------------------------
// Main MFMA kernel. grid = (NP/SRC_PER_BLOCK, MP/TGT_PER_BLOCK, 2*BQ)
//                        = (8, 4, 32) = 1024 blocks, 4/CU.
// Each wave holds FR=4 B-fragments (128 sources); each staged A-fragment
// ds_read_b128 feeds 4 MFMAs. Partial per-source mins (over this block's
// 1024 targets) merge across y-blocks via uint atomicMin (d2 >= 0).
// ---------------------------------------------------------------------------
__global__ __launch_bounds__(TPB) void chamfer_main_kernel(
    const float* __restrict__ srcp, const float* __restrict__ tgtp,
    const unsigned short* __restrict__ table,
    unsigned int* __restrict__ minbuf) {
    const int gz  = blockIdx.z;
    const int dir = gz >> 4;
    const int b   = gz & 15;
    const float* S = dir ? (tgtp + (size_t)b * MP * 3) : (srcp + (size_t)b * NP * 3);
    const unsigned short* At =
        table + ((size_t)gz * 4096 + (size_t)blockIdx.y * TGT_PER_BLOCK) * 16;
    unsigned int* mb = minbuf + (size_t)gz * 4096;

    const int tid  = threadIdx.x;
    const int lane = tid & 63;
    const int half = lane >> 5;
    const int col  = lane & 31;
    const int wave = tid >> 6;

    __shared__ unsigned short sh[CHUNK * 16];  // 8 KB
    const unsigned short ONE = 0x3F80;

    // ---- FR B-fragments (source side), fixed for the whole kernel ----
    Frag bf[FR];
#pragma unroll
    for (int f = 0; f < FR; ++f) {
        const int sidx = blockIdx.x * SRC_PER_BLOCK + (wave * FR + f) * 32 + col;
        const float* sp = S + (size_t)sidx * 3;
        float x = sp[0], y = sp[1], z = sp[2];
        unsigned short uh0 = f2bf(-2.0f * x), uh1 = f2bf(-2.0f * y), uh2 = f2bf(-2.0f * z);
        unsigned short ul0 = f2bf(-2.0f * x - bf2f(uh0));
        unsigned short ul1 = f2bf(-2.0f * y - bf2f(uh1));
        unsigned short ul2 = f2bf(-2.0f * z - bf2f(uh2));
        float s2 = fmaf(x, x, fmaf(y, y, z * z));
        unsigned short s2h = f2bf(s2), s2l = f2bf(s2 - bf2f(s2h));
        if (half == 0) {  // k = 0..7
            bf[f].u[0] = uh0; bf[f].u[1] = uh1; bf[f].u[2] = uh2;
            bf[f].u[3] = ul0; bf[f].u[4] = ul1; bf[f].u[5] = ul2;
            bf[f].u[6] = uh0; bf[f].u[7] = uh1;
        } else {          // k = 8..15
            bf[f].u[0] = uh2; bf[f].u[1] = ONE; bf[f].u[2] = ONE;
            bf[f].u[3] = s2h; bf[f].u[4] = s2l;
            bf[f].u[5] = 0;   bf[f].u[6] = 0;  bf[f].u[7] = 0;
        }
    }

    float accm[FR];
#pragma unroll
    for (int f = 0; f < FR; ++f) accm[f] = __int_as_float(0x7F800000);

    const f32x16 zc = {};  // hoisted zero accumulator input

    for (int c = 0; c < TGT_PER_BLOCK / CHUNK; ++c) {  // 4 chunks
        // ---- stage 8 KB of pre-expanded A-planes (coalesced, no expansion) ----
        {
            const int4* gp = (const int4*)(At + (size_t)c * CHUNK * 16);
            int4* sp4 = (int4*)sh;
            sp4[tid]       = gp[tid];
            sp4[tid + 256] = gp[tid + 256];
        }
        __syncthreads();

        // ---- 8 sub-chunks; each A-fragment feeds FR MFMAs ----
#pragma unroll
        for (int sc = 0; sc < CHUNK / 32; ++sc) {
            Frag a;
            a.i4 = *(const int4*)&sh[sc * 512 + col * 16 + half * 8];
#pragma unroll
            for (int f = 0; f < FR; ++f) {
                f32x16 d = __builtin_amdgcn_mfma_f32_32x32x16_bf16(a.v, bf[f].v, zc, 0, 0, 0);
                float m0 = fminf(fminf(d[0], d[1]), d[2]);
                float m1 = fminf(fminf(d[3], d[4]), d[5]);
                float m2 = fminf(fminf(d[6], d[7]), d[8]);
                float m3 = fminf(fminf(d[9], d[10]), d[11]);
                float m4 = fminf(fminf(d[12], d[13]), d[14]);
                float t0 = fminf(fminf(m0, m1), m2);
                float t1 = fminf(fminf(m3, m4), d[15]);
                accm[f] = fminf(fminf(accm[f], t0), t1);
            }
        }
        __syncthreads();
    }

    // ---- epilogue: fold row-halves, clamp, merge across y-blocks ----
#pragma unroll
    for (int f = 0; f < FR; ++f) {
        float m = fminf(accm[f], __shfl_xor(accm[f], 32, 64));
        m = fmaxf(m, 0.0f);
        if (lane < 32) {
            const int sidx = blockIdx.x * SRC_PER_BLOCK + (wave * FR + f) * 32 + col;
            atomicMin(&mb[sidx], __float_as_uint(m));
        }
    }
}

// ---------------------------------------------------------------------------
// Reduce: one block per (dir, b): sum 4096 mins, weight, accumulate scalar.
// ---------------------------------------------------------------------------
__global__ __launch_bounds__(TPB) void chamfer_reduce_kernel(
    const float* __restrict__ minbuf, const float* __restrict__ weights,
    float* __restrict__ out) {
    const int idx = blockIdx.x;  // dir*16 + b
    const int b = idx & 15;
    const float* m0 = minbuf + (size_t)idx * 4096;

    float s = 0.0f;
    for (int i = threadIdx.x; i < 4096; i += TPB) s += m0[i];
#pragma unroll
    for (int off = 32; off > 0; off >>= 1) s += __shfl_down(s, off, 64);

    __shared__ float red[TPB / 64];
    if ((threadIdx.x & 63) == 0) red[threadIdx.x >> 6] = s;
    __syncthreads();
    if (threadIdx.x == 0) {
        float tot = red[0] + red[1] + red[2] + red[3];
        atomicAdd(out, weights[b] * tot * (1.0f / (4096.0f * (float)BQ)));
    }
}

// ---------------------------------------------------------------------------
// Fallback (R3-proven): full-M single kernel, no workspace table.
// ---------------------------------------------------------------------------
__global__ void chamfer_zero_kernel(float* __restrict__ out) { out[0] = 0.0f; }

__global__ __launch_bounds__(TPB) void chamfer_mfma_fb_kernel(
    const float* __restrict__ srcp, const float* __restrict__ tgtp,
    const float* __restrict__ wts, float* __restrict__ out) {
    const int gy = blockIdx.y, dir = gy >> 4, b = gy & 15;
    const float* S = dir ? (tgtp + (size_t)b * MP * 3) : (srcp + (size_t)b * NP * 3);
    const float* T = dir ? (srcp + (size_t)b * NP * 3) : (tgtp + (size_t)b * MP * 3);
    const int tid = threadIdx.x, lane = tid & 63, half = lane >> 5,
              col = tid & 31, wave = tid >> 6;
    __shared__ unsigned short sh[256 * 16];
    __shared__ float partial[4];
    const unsigned short ONE = 0x3F80;
    Frag bfrag;
    {
        const int sidx = blockIdx.x * 128 + wave * 32 + (lane & 31);
        const float* sp = S + (size_t)sidx * 3;
        float x = sp[0], y = sp[1], z = sp[2];
        unsigned short uh0 = f2bf(-2.0f * x), uh1 = f2bf(-2.0f * y), uh2 = f2bf(-2.0f * z);
        unsigned short ul0 = f2bf(-2.0f * x - bf2f(uh0));
        unsigned short ul1 = f2bf(-2.0f * y - bf2f(uh1));
        unsigned short ul2 = f2bf(-2.0f * z - bf2f(uh2));
        float s2 = fmaf(x, x, fmaf(y, y, z * z));
        unsigned short s2h = f2bf(s2), s2l = f2bf(s2 - bf2f(s2h));
        if (half == 0) {
            bfrag.u[0] = uh0; bfrag.u[1] = uh1; bfrag.u[2] = uh2;
            bfrag.u[3] = ul0; bfrag.u[4] = ul1; bfrag.u[5] = ul2;
            bfrag.u[6] = uh0; bfrag.u[7] = uh1;
        } else {
            bfrag.u[0] = uh2; bfrag.u[1] = ONE; bfrag.u[2] = ONE;
            bfrag.u[3] = s2h; bfrag.u[4] = s2l;
            bfrag.u[5] = 0;   bfrag.u[6] = 0;  bfrag.u[7] = 0;
        }
    }
    float accm = __int_as_float(0x7F800000);
    for (int c = 0; c < MP / 256; ++c) {
        {
            const float* tp = T + (size_t)(c * 256 + tid) * 3;
            float x = tp[0], y = tp[1], z = tp[2];
            unsigned short xh = f2bf(x), yh = f2bf(y), zh = f2bf(z);
            unsigned short xl = f2bf(x - bf2f(xh)), yl = f2bf(y - bf2f(yh)),
                           zl = f2bf(z - bf2f(zh));
            float t2 = fmaf(x, x, fmaf(y, y, z * z));
            unsigned short t2h = f2bf(t2), t2l = f2bf(t2 - bf2f(t2h));
            Frag p0, p1;
            p0.u[0] = xh; p0.u[1] = yh; p0.u[2] = zh;
            p0.u[3] = xh; p0.u[4] = yh; p0.u[5] = zh;
            p0.u[6] = xl; p0.u[7] = yl;
            p1.u[0] = zl; p1.u[1] = t2h; p1.u[2] = t2l;
            p1.u[3] = ONE; p1.u[4] = ONE; p1.u[5] = 0; p1.u[6] = 0; p1.u[7] = 0;
            const int sub = tid >> 5, row = tid & 31;
            *(int4*)&sh[sub * 512 + row * 8] = p0.i4;
            *(int4*)&sh[sub * 512 + 256 + row * 8] = p1.i4;
        }
        __syncthreads();
        const f32x16 zc = {};
#pragma unroll
        for (int sc = 0; sc < 8; ++sc) {
            Frag a;
            a.i4 = *(const int4*)&sh[sc * 512 + half * 256 + col * 8];
            f32x16 d = __builtin_amdgcn_mfma_f32_32x32x16_bf16(a.v, bfrag.v, zc, 0, 0, 0);
            float m0 = fminf(fminf(d[0], d[1]), d[2]);
            float m1 = fminf(fminf(d[3], d[4]), d[5]);
            float m2 = fminf(fminf(d[6], d[7]), d[8]);
            float m3 = fminf(fminf(d[9], d[10]), d[11]);
            float m4 = fminf(fminf(d[12], d[13]), d[14]);
            accm = fminf(accm, fminf(fminf(fminf(m0, m1), m2),
                                     fminf(fminf(m3, m4), d[15])));
        }
        __syncthreads();
    }
    float m = fminf(accm, __shfl_xor(accm, 32, 64));
    m = fmaxf(m, 0.0f);
#pragma unroll
    for (int off = 16; off > 0; off >>= 1) m += __shfl_xor(m, off, 64);
    if (lane == 0) partial[wave] = m;
    __syncthreads();
    if (tid == 0) {
        float v = partial[0] + partial[1] + partial[2] + partial[3];
        atomicAdd(out, v * wts[b] * (1.0f / ((float)NP * (float)BQ)));
    }
}

// ---------------------------------------------------------------------------
extern "C" void kernel_launch(void* const* d_in, const int* in_sizes, int n_in,
                              void* d_out, int out_size, void* d_ws, size_t ws_size,
                              hipStream_t stream) {
    const float* src = (const float*)d_in[0];
    const float* tgt = (const float*)d_in[1];
    const float* wts = (const float*)d_in[2];
    float* out = (float*)d_out;

    const size_t MINBUF_BYTES = (size_t)2 * BQ * 4096 * 4;        // 512 KB
    const size_t TABLE_BYTES  = (size_t)2 * BQ * 4096 * 32;       // 4 MB

    if (ws_size >= MINBUF_BYTES + TABLE_BYTES) {
        unsigned int* minbuf = (unsigned int*)d_ws;
        unsigned short* table = (unsigned short*)((char*)d_ws + MINBUF_BYTES);

        chamfer_prep_kernel<<<(2 * BQ * 4096) / TPB, TPB, 0, stream>>>(
            src, tgt, table, minbuf, out);

        dim3 grid(NP / SRC_PER_BLOCK, MP / TGT_PER_BLOCK, 2 * BQ);  // (8,4,32)
        chamfer_main_kernel<<<grid, TPB, 0, stream>>>(src, tgt, table, minbuf);

        chamfer_reduce_kernel<<<2 * BQ, TPB, 0, stream>>>(
            (const float*)minbuf, wts, out);
    } else {
        chamfer_zero_kernel<<<1, 1, 0, stream>>>(out);
        dim3 grid(NP / 128, 2 * BQ);
        chamfer_mfma_fb_kernel<<<grid, TPB, 0, stream>>>(src, tgt, wts, out);
    }
}